// Round 2
// baseline (156.585 us; speedup 1.0000x reference)
//
#include <hip/hip_runtime.h>

// TopologyAwareAttention, single fused kernel + tiny memset.
//  f(t) = sum_e relu(t*w1[e]+b1[e]) * mean_h(w2[e,h]) + mean(b2)   (head-mean first)
//  centers on 16x16 grid => d2 = dx^2+dy^2 in [0,450] => 451-entry LUT per batch
//  mean distance via cell histogram: sum = SUM_{c1,c2} h[c1] h[c2] sqrt(d2(c1,c2))
// Phases inside ONE kernel (manual grid barrier, 450 blocks co-resident by
// __launch_bounds__(256,2): cap 512 blocks >= 450 => no deadlock):
//  P1: per-wave argmax centers (1800 waves) + histogram atomics
//  P2: blocks 0,1 compute mean + LUT; other blocks prefetch idx_s meanwhile
//  P3: memory-bound apply, float4 in/out

#define NQ    900
#define NB    2
#define LUT_N 451
#define NBLK  450

__device__ inline void grid_barrier(int* count, int* gen, int target) {
    __syncthreads();
    if (threadIdx.x == 0) {
        __threadfence();
        if (atomicAdd(count, 1) == NBLK - 1) {
            *count = 0;
            __threadfence();
            atomicExch(gen, target);
        } else {
            while (atomicAdd(gen, 0) < target) __builtin_amdgcn_s_sleep(2);
        }
        __threadfence();
    }
    __syncthreads();
}

__global__ __launch_bounds__(256, 2)
void fused_kernel(const float* __restrict__ attn,
                  const float* __restrict__ ref,
                  const float* __restrict__ lam_p,
                  const float* __restrict__ w1,
                  const float* __restrict__ b1,
                  const float* __restrict__ w2,
                  const float* __restrict__ b2,
                  float* __restrict__ out,
                  int* __restrict__ ws_i) {
    int*   count = ws_i;                       // zeroed by memset node
    int*   gen   = ws_i + 1;                   // zeroed
    int*   hist  = ws_i + 16;                  // [2][256], zeroed
    int*   cent  = ws_i + 1024;                // [1800]
    float* lut   = (float*)(ws_i + 1024 + NB * NQ);  // [2][451]

    __shared__ int   idx_s[NQ];
    __shared__ float lut_s[LUT_N];             // doubles as wbar scratch in P2
    __shared__ int   hsh[256];
    __shared__ float wsum[4];

    const int tid  = threadIdx.x;
    const int lane = tid & 63;
    const int wave = tid >> 6;
    const int blk  = blockIdx.x;

    // ---------------- phase 1: centers argmax + cell histogram ----------------
    {
        int q = blk * 4 + wave;                // exactly 0..1799
        const float* p = ref + (size_t)q * 256;
        float bv = p[lane];
        int   bi = lane;
        #pragma unroll
        for (int k = 1; k < 4; ++k) {
            float v = p[lane + 64 * k];
            if (v > bv) { bv = v; bi = lane + 64 * k; }   // strict > keeps first max
        }
        #pragma unroll
        for (int off = 32; off >= 1; off >>= 1) {
            float ov = __shfl_down(bv, off, 64);
            int   oi = __shfl_down(bi, off, 64);
            if (ov > bv || (ov == bv && oi < bi)) { bv = ov; bi = oi; }
        }
        if (lane == 0) {
            cent[q] = bi;                      // bi = iy*16 + ix
            int b = (q >= NQ) ? 1 : 0;
            atomicAdd(&hist[b * 256 + bi], 1);
        }
    }

    grid_barrier(count, gen, 1);

    // rows r0..r0+3 (linear over (b,i), 1800 rows); 900 % 4 == 0 => same batch
    const int r0 = blk * 4;
    const int b3 = (r0 >= NQ) ? 1 : 0;
    const int i0 = r0 - b3 * NQ;

    // all blocks prefetch their j-column centers while blocks 0,1 do stats
    for (int k = tid; k < NQ; k += 256) idx_s[k] = cent[b3 * NQ + k];

    // ---------------- phase 2: mean + LUT (blocks 0,1 only) ----------------
    if (blk < NB) {
        int b = blk;
        hsh[tid] = hist[b * 256 + tid];
        __syncthreads();
        float local = 0.f;
        int h2v = hsh[tid];                    // fixed c2 = tid per thread
        if (h2v) {
            int ix2 = tid & 15, iy2 = tid >> 4;
            for (int c1 = 0; c1 < 256; ++c1) {
                int h1 = hsh[c1];              // broadcast read, conflict-free
                if (h1) {
                    int dx = (c1 & 15) - ix2;
                    int dy = (c1 >> 4) - iy2;
                    local += (float)h1 * sqrtf((float)(dx * dx + dy * dy));
                }
            }
            local *= (float)h2v;
        }
        #pragma unroll
        for (int off = 32; off >= 1; off >>= 1) local += __shfl_down(local, off, 64);
        if (lane == 0) wsum[wave] = local;
        __syncthreads();
        float tot  = wsum[0] + wsum[1] + wsum[2] + wsum[3];
        float mean = tot * (1.f / 15.f) * (1.f / ((float)NQ * (float)NQ));
        float inv  = 1.f / (mean + 1e-6f);

        float s8 = 0.f;
        #pragma unroll
        for (int h = 0; h < 8; ++h) s8 += w2[tid * 8 + h];
        lut_s[tid] = s8 * 0.125f;              // wbar scratch (overwritten in P3)
        __syncthreads();
        float b2bar = 0.125f * (b2[0] + b2[1] + b2[2] + b2[3] +
                                b2[4] + b2[5] + b2[6] + b2[7]);
        float lam = lam_p[0];
        for (int s = tid; s < LUT_N; s += 256) {
            float t   = sqrtf((float)s) * (1.f / 15.f) * inv;
            float acc = b2bar;
            for (int i = 0; i < 256; ++i) {
                float hv = fmaf(t, w1[i], b1[i]);
                acc = fmaf(fmaxf(hv, 0.f), lut_s[i], acc);
            }
            lut[b * LUT_N + s] = lam * acc;
        }
    }

    grid_barrier(count, gen, 2);

    // ---------------- phase 3: apply (memory-bound) ----------------
    for (int k = tid; k < LUT_N; k += 256) lut_s[k] = lut[b3 * LUT_N + k];
    __syncthreads();

    for (int e = tid; e < 900; e += 256) {     // 4 rows x 225 float4 per block
        int lr  = e / 225;
        int c4  = (e - lr * 225) * 4;
        int i   = i0 + lr;
        int ci  = idx_s[i];
        int ixi = ci & 15, iyi = ci >> 4;
        size_t base = ((size_t)(b3 * NQ + i)) * NQ + c4;
        float4 a = *(const float4*)(attn + base);
        float r[4] = {a.x, a.y, a.z, a.w};
        #pragma unroll
        for (int u = 0; u < 4; ++u) {
            int cj = idx_s[c4 + u];
            int dx = ixi - (cj & 15), dy = iyi - (cj >> 4);
            r[u] += lut_s[dx * dx + dy * dy];
        }
        *(float4*)(out + base) = make_float4(r[0], r[1], r[2], r[3]);
    }
}

extern "C" void kernel_launch(void* const* d_in, const int* in_sizes, int n_in,
                              void* d_out, int out_size, void* d_ws, size_t ws_size,
                              hipStream_t stream) {
    const float* attn = (const float*)d_in[0];   // [2,900,900]
    const float* ref  = (const float*)d_in[1];   // [2,900,16,16]
    const float* lam  = (const float*)d_in[2];
    const float* w1   = (const float*)d_in[3];   // [256]
    const float* b1   = (const float*)d_in[4];   // [256]
    const float* w2   = (const float*)d_in[5];   // [256,8]
    const float* b2   = (const float*)d_in[6];   // [8]
    float* out = (float*)d_out;
    int*   ws  = (int*)d_ws;

    // zero: count, gen, hist[2][256] (first 4 KB covers all)
    hipMemsetAsync(ws, 0, 4096, stream);
    fused_kernel<<<NBLK, 256, 0, stream>>>(attn, ref, lam, w1, b1, w2, b2, out, ws);
}

// Round 3
// 155.676 us; speedup vs baseline: 1.0058x; 1.0058x over previous
//
#include <hip/hip_runtime.h>

// TopologyAwareAttention — 2 kernels, no grid barrier, no memset.
//  f(t) = sum_e relu(t*w1[e]+b1[e]) * mean_h(w2[e,h]) + mean(b2)   (head-mean first)
//  centers on 16x16 grid => d2 = dx^2+dy^2 in [0,450] => 451-entry LUT per batch
//  mean distance via cell histogram: sum = SUM_{c1,c2} h[c1] h[c2] sqrt(d2(c1,c2))
// R2 lesson: device-atomic spin barrier costs ~40 us/crossing — never again.
// Instead every apply block redundantly recomputes stats+LUT (~3 us, parallel,
// deterministic => identical results across blocks).

#define NQ    900
#define NB    2
#define LUT_N 451

__global__ __launch_bounds__(256) void centers_kernel(const float* __restrict__ ref,
                                                      int* __restrict__ centers) {
    // one wave per query; 450 blocks x 4 waves = 1800 queries
    int wave = threadIdx.x >> 6;
    int lane = threadIdx.x & 63;
    int q = blockIdx.x * 4 + wave;          // < 1800 always
    const float* p = ref + (size_t)q * 256;
    float bv = p[lane];
    int   bi = lane;
    #pragma unroll
    for (int k = 1; k < 4; ++k) {
        float v = p[lane + 64 * k];
        if (v > bv) { bv = v; bi = lane + 64 * k; }   // strict > keeps first max
    }
    #pragma unroll
    for (int off = 32; off >= 1; off >>= 1) {
        float ov = __shfl_down(bv, off, 64);
        int   oi = __shfl_down(bi, off, 64);
        if (ov > bv || (ov == bv && oi < bi)) { bv = ov; bi = oi; }
    }
    if (lane == 0) centers[q] = bi;         // bi = iy*16 + ix
}

__global__ __launch_bounds__(256)
void fused_apply(const float* __restrict__ attn,
                 const int* __restrict__ cent,
                 const float* __restrict__ lam_p,
                 const float* __restrict__ w1,
                 const float* __restrict__ b1,
                 const float* __restrict__ w2,
                 const float* __restrict__ b2,
                 float* __restrict__ out) {
    const int b   = blockIdx.y;
    const int tid = threadIdx.x;
    const int lane = tid & 63;
    const int wave = tid >> 6;

    __shared__ int   idx_s[NQ];
    __shared__ int   hsh[256];
    __shared__ float w1s[256], b1s[256], wbar[256];
    __shared__ float lut_s[LUT_N];
    __shared__ float wsum[4];

    // stage centers + weights
    for (int k = tid; k < NQ; k += 256) idx_s[k] = cent[b * NQ + k];
    hsh[tid] = 0;
    w1s[tid] = w1[tid];
    b1s[tid] = b1[tid];
    {
        float s8 = 0.f;
        #pragma unroll
        for (int h = 0; h < 8; ++h) s8 += w2[tid * 8 + h];
        wbar[tid] = s8 * 0.125f;
    }
    __syncthreads();

    // cell histogram (LDS atomics, ~4 adds/thread)
    for (int k = tid; k < NQ; k += 256) atomicAdd(&hsh[idx_s[k]], 1);
    __syncthreads();

    // pairwise distance sum via histogram: thread owns c2 = tid
    float local = 0.f;
    {
        int h2v = hsh[tid];
        if (h2v) {
            int ix2 = tid & 15, iy2 = tid >> 4;
            for (int c1 = 0; c1 < 256; ++c1) {
                int h1 = hsh[c1];              // broadcast read, conflict-free
                if (h1) {
                    int dx = (c1 & 15) - ix2;
                    int dy = (c1 >> 4) - iy2;
                    local += (float)h1 * sqrtf((float)(dx * dx + dy * dy));
                }
            }
            local *= (float)h2v;
        }
    }
    #pragma unroll
    for (int off = 32; off >= 1; off >>= 1) local += __shfl_down(local, off, 64);
    if (lane == 0) wsum[wave] = local;
    __syncthreads();

    float tot  = wsum[0] + wsum[1] + wsum[2] + wsum[3];
    float mean = tot * (1.f / 15.f) * (1.f / ((float)NQ * (float)NQ));
    float inv  = 1.f / (mean + 1e-6f);
    float b2bar = 0.125f * (b2[0] + b2[1] + b2[2] + b2[3] +
                            b2[4] + b2[5] + b2[6] + b2[7]);
    float lam = lam_p[0];

    // 451-entry LUT: <=2 entries/thread, 256-term relu-dot each
    for (int s = tid; s < LUT_N; s += 256) {
        float t   = sqrtf((float)s) * (1.f / 15.f) * inv;
        float acc = b2bar;
        for (int i = 0; i < 256; ++i) {
            float hv = fmaf(t, w1s[i], b1s[i]);
            acc = fmaf(fmaxf(hv, 0.f), wbar[i], acc);
        }
        lut_s[s] = lam * acc;
    }
    __syncthreads();

    // apply: one float4 per thread
    int t4 = blockIdx.x * 256 + tid;
    if (t4 >= NQ * NQ / 4) return;             // 202500 float4s per batch
    int i  = t4 / 225;                         // 225 float4 per row
    int j0 = (t4 - i * 225) * 4;
    int ci = idx_s[i];
    int ixi = ci & 15, iyi = ci >> 4;
    size_t base = (size_t)b * (NQ * NQ) + (size_t)i * NQ + j0;
    float4 a = *(const float4*)(attn + base);
    float r[4] = {a.x, a.y, a.z, a.w};
    #pragma unroll
    for (int u = 0; u < 4; ++u) {
        int cj = idx_s[j0 + u];
        int dx = ixi - (cj & 15), dy = iyi - (cj >> 4);
        r[u] += lut_s[dx * dx + dy * dy];
    }
    *(float4*)(out + base) = make_float4(r[0], r[1], r[2], r[3]);
}

extern "C" void kernel_launch(void* const* d_in, const int* in_sizes, int n_in,
                              void* d_out, int out_size, void* d_ws, size_t ws_size,
                              hipStream_t stream) {
    const float* attn = (const float*)d_in[0];   // [2,900,900]
    const float* ref  = (const float*)d_in[1];   // [2,900,16,16]
    const float* lam  = (const float*)d_in[2];
    const float* w1   = (const float*)d_in[3];   // [256]
    const float* b1   = (const float*)d_in[4];   // [256]
    const float* w2   = (const float*)d_in[5];   // [256,8]
    const float* b2   = (const float*)d_in[6];   // [8]
    float* out = (float*)d_out;
    int*   cent = (int*)d_ws;                    // [1800]

    centers_kernel<<<450, 256, 0, stream>>>(ref, cent);
    fused_apply<<<dim3((NQ * NQ / 4 + 255) / 256, NB), 256, 0, stream>>>(
        attn, cent, lam, w1, b1, w2, b2, out);
}

// Round 4
// 94.227 us; speedup vs baseline: 1.6618x; 1.6521x over previous
//
#include <hip/hip_runtime.h>

// TopologyAwareAttention — 3 lean kernels, stats computed ONCE (2 blocks).
//  f(t) = sum_e relu(t*w1[e]+b1[e]) * mean_h(w2[e,h]) + mean(b2)   (head-mean first)
//  centers on 16x16 grid => d2 = dx^2+dy^2 in [0,450] => 451-entry LUT per batch
//  mean distance via cell histogram: sum = SUM_{c1,c2} h[c1] h[c2] sqrt(d2)
// R2 lesson: global spin barrier ~40us/crossing. R3 lesson: per-block redundant
// stats+LUT across 1584 blocks = ~90us of VALU (precise sqrt chain dominates).
// Cost model: dur = ~40us harness ws-fill + ~6us/node + kernel times.

#define NQ    900
#define NB    2
#define LUT_N 451

__global__ __launch_bounds__(256) void centers_kernel(const float* __restrict__ ref,
                                                      int* __restrict__ centers) {
    // one wave per query; 450 blocks x 4 waves = 1800 queries
    int wave = threadIdx.x >> 6;
    int lane = threadIdx.x & 63;
    int q = blockIdx.x * 4 + wave;          // < 1800 always
    const float* p = ref + (size_t)q * 256;
    float bv = p[lane];
    int   bi = lane;
    #pragma unroll
    for (int k = 1; k < 4; ++k) {
        float v = p[lane + 64 * k];
        if (v > bv) { bv = v; bi = lane + 64 * k; }   // strict > keeps first max
    }
    #pragma unroll
    for (int off = 32; off >= 1; off >>= 1) {
        float ov = __shfl_down(bv, off, 64);
        int   oi = __shfl_down(bi, off, 64);
        if (ov > bv || (ov == bv && oi < bi)) { bv = ov; bi = oi; }
    }
    if (lane == 0) centers[q] = bi;         // bi = iy*16 + ix
}

__global__ __launch_bounds__(256)
void lutk(const int* __restrict__ cent,
          const float* __restrict__ lam_p,
          const float* __restrict__ w1,
          const float* __restrict__ b1,
          const float* __restrict__ w2,
          const float* __restrict__ b2,
          float* __restrict__ lut) {
    const int b    = blockIdx.x;            // 2 blocks
    const int tid  = threadIdx.x;
    const int lane = tid & 63;
    const int wave = tid >> 6;

    __shared__ int   hsh[256];
    __shared__ float sqs[LUT_N];            // sqrt table: sqs[s]=sqrt(s)
    __shared__ float wbar[256];
    __shared__ float wsum[4];

    hsh[tid] = 0;
    for (int s = tid; s < LUT_N; s += 256) sqs[s] = sqrtf((float)s);
    {
        float s8 = 0.f;
        #pragma unroll
        for (int h = 0; h < 8; ++h) s8 += w2[tid * 8 + h];
        wbar[tid] = s8 * 0.125f;
    }
    __syncthreads();

    for (int k = tid; k < NQ; k += 256) atomicAdd(&hsh[cent[b * NQ + k]], 1);
    __syncthreads();

    // pairwise distance sum via histogram; thread owns c2 = tid
    float local = 0.f;
    {
        int h2v = hsh[tid];
        if (h2v) {
            int ix2 = tid & 15, iy2 = tid >> 4;
            for (int c1 = 0; c1 < 256; ++c1) {
                int h1 = hsh[c1];                       // broadcast read
                int dx = (c1 & 15) - ix2;
                int dy = (c1 >> 4) - iy2;
                local += (float)h1 * sqs[dx * dx + dy * dy];
            }
            local *= (float)h2v;
        }
    }
    #pragma unroll
    for (int off = 32; off >= 1; off >>= 1) local += __shfl_down(local, off, 64);
    if (lane == 0) wsum[wave] = local;
    __syncthreads();

    float tot  = wsum[0] + wsum[1] + wsum[2] + wsum[3];
    float mean = tot * (1.f / 15.f) * (1.f / ((float)NQ * (float)NQ));
    float inv  = 1.f / (mean + 1e-6f);
    float b2bar = 0.125f * (b2[0] + b2[1] + b2[2] + b2[3] +
                            b2[4] + b2[5] + b2[6] + b2[7]);
    float lam = lam_p[0];

    for (int s = tid; s < LUT_N; s += 256) {
        float t   = sqs[s] * (1.f / 15.f) * inv;
        float acc = b2bar;
        for (int i = 0; i < 256; ++i) {
            float hv = fmaf(t, w1[i], b1[i]);           // w1/b1 L1-cached scalarish
            acc = fmaf(fmaxf(hv, 0.f), wbar[i], acc);
        }
        lut[b * LUT_N + s] = lam * acc;
    }
}

__global__ __launch_bounds__(256) void apply_kernel(const float* __restrict__ attn,
                                                    const int* __restrict__ centers,
                                                    const float* __restrict__ lut,
                                                    float* __restrict__ out) {
    int b = blockIdx.y;
    __shared__ float lut_s[LUT_N];
    __shared__ int   idx_s[NQ];
    for (int k = threadIdx.x; k < LUT_N; k += 256) lut_s[k] = lut[b * LUT_N + k];
    for (int k = threadIdx.x; k < NQ;    k += 256) idx_s[k] = centers[b * NQ + k];
    __syncthreads();
    int t4 = blockIdx.x * 256 + threadIdx.x;    // one float4 per thread
    if (t4 >= NQ * NQ / 4) return;              // 202500 per batch
    int i  = t4 / 225;                          // 225 float4 per row
    int j0 = (t4 - i * 225) * 4;
    int ci = idx_s[i];
    int ixi = ci & 15, iyi = ci >> 4;
    size_t base = (size_t)b * (NQ * NQ) + (size_t)i * NQ + j0;
    float4 a = *(const float4*)(attn + base);
    float r[4] = {a.x, a.y, a.z, a.w};
    #pragma unroll
    for (int u = 0; u < 4; ++u) {
        int cj = idx_s[j0 + u];
        int dx = ixi - (cj & 15), dy = iyi - (cj >> 4);
        r[u] += lut_s[dx * dx + dy * dy];
    }
    *(float4*)(out + base) = make_float4(r[0], r[1], r[2], r[3]);
}

extern "C" void kernel_launch(void* const* d_in, const int* in_sizes, int n_in,
                              void* d_out, int out_size, void* d_ws, size_t ws_size,
                              hipStream_t stream) {
    const float* attn = (const float*)d_in[0];   // [2,900,900]
    const float* ref  = (const float*)d_in[1];   // [2,900,16,16]
    const float* lam  = (const float*)d_in[2];
    const float* w1   = (const float*)d_in[3];   // [256]
    const float* b1   = (const float*)d_in[4];   // [256]
    const float* w2   = (const float*)d_in[5];   // [256,8]
    const float* b2   = (const float*)d_in[6];   // [8]
    float* out = (float*)d_out;

    int*   cent = (int*)d_ws;                    // [1800]
    float* lut  = (float*)((char*)d_ws + 1800 * 4);  // [2][451]

    centers_kernel<<<450, 256, 0, stream>>>(ref, cent);
    lutk<<<NB, 256, 0, stream>>>(cent, lam, w1, b1, w2, b2, lut);
    apply_kernel<<<dim3((NQ * NQ / 4 + 255) / 256, NB), 256, 0, stream>>>(attn, cent, lut, out);
}